// Round 1
// baseline (2889.353 us; speedup 1.0000x reference)
//
#include <hip/hip_runtime.h>
#include <math.h>

#define NN 50000
#define EE 800000
#define FF 64
#define LL 2
#define TT 12
#define NF (NN * FF)

// ---------------- CSR build ----------------

__global__ __launch_bounds__(256) void k_deg(const int* __restrict__ dst, int* __restrict__ deg) {
  int e = blockIdx.x * 256 + threadIdx.x;
  if (e < EE) atomicAdd(&deg[dst[e]], 1);
}

__global__ __launch_bounds__(256) void k_scan1(const int* __restrict__ deg, int* __restrict__ rowptr,
                                               int* __restrict__ bsum) {
  __shared__ int s[256];
  int i = blockIdx.x * 256 + threadIdx.x;
  int v = (i < NN) ? deg[i] : 0;
  s[threadIdx.x] = v;
  __syncthreads();
  for (int off = 1; off < 256; off <<= 1) {
    int t = (threadIdx.x >= off) ? s[threadIdx.x - off] : 0;
    __syncthreads();
    s[threadIdx.x] += t;
    __syncthreads();
  }
  if (i < NN) rowptr[i + 1] = s[threadIdx.x];
  if (threadIdx.x == 255) bsum[blockIdx.x] = s[255];
}

__global__ __launch_bounds__(256) void k_scan2(const int* __restrict__ bsum, int* __restrict__ boff, int nb) {
  __shared__ int s[256];
  int v = (threadIdx.x < nb) ? bsum[threadIdx.x] : 0;
  s[threadIdx.x] = v;
  __syncthreads();
  for (int off = 1; off < 256; off <<= 1) {
    int t = (threadIdx.x >= off) ? s[threadIdx.x - off] : 0;
    __syncthreads();
    s[threadIdx.x] += t;
    __syncthreads();
  }
  boff[threadIdx.x] = s[threadIdx.x] - v;  // exclusive
}

__global__ __launch_bounds__(256) void k_scan3(const int* __restrict__ deg, int* __restrict__ rowptr,
                                               int* __restrict__ fill, float* __restrict__ invdeg,
                                               const int* __restrict__ boff) {
  int i = blockIdx.x * 256 + threadIdx.x;
  if (i >= NN) return;
  int incl = rowptr[i + 1] + boff[blockIdx.x];
  rowptr[i + 1] = incl;
  int d = deg[i];
  fill[i] = incl - d;
  invdeg[i] = (d > 0) ? (1.0f / (float)d) : 0.0f;
  if (i == 0) rowptr[0] = 0;
}

__global__ __launch_bounds__(256) void k_scatter(const int* __restrict__ src, const int* __restrict__ dst,
                                                 int* __restrict__ fill, int* __restrict__ col) {
  int e = blockIdx.x * 256 + threadIdx.x;
  if (e >= EE) return;
  int slot = atomicAdd(&fill[dst[e]], 1);
  col[slot] = src[e];
}

// ---------------- mean aggregation (CSR gather-sum), wave per node ----------------

__global__ __launch_bounds__(256) void k_agg(const float* __restrict__ feat, float* __restrict__ outp,
                                             const int* __restrict__ rowptr, const int* __restrict__ col,
                                             const float* __restrict__ invdeg) {
  int v = blockIdx.x * 4 + (threadIdx.x >> 6);
  if (v >= NN) return;
  int lane = threadIdx.x & 63;
  int s = rowptr[v], e = rowptr[v + 1];
  float sum = 0.f;
  int i = s;
  for (; i + 4 <= e; i += 4) {
    int c0 = col[i + 0], c1 = col[i + 1], c2 = col[i + 2], c3 = col[i + 3];
    float f0 = feat[c0 * 64 + lane];
    float f1 = feat[c1 * 64 + lane];
    float f2 = feat[c2 * 64 + lane];
    float f3 = feat[c3 * 64 + lane];
    sum += f0; sum += f1; sum += f2; sum += f3;
  }
  for (; i < e; ++i) sum += feat[col[i] * 64 + lane];
  outp[v * 64 + lane] = sum * invdeg[v];
}

// ---------------- fused GEMM + GRU cell ----------------
// pre_u = aggX@W[2] + aggH@W[3] + b2+b3 ; pre_c = aggX@W[4] + aggH@W[5] + b4+b5
// h' = sigmoid(pre_u)*h + (1-sigmoid(pre_u))*tanh(pre_c), in place over h.
// Tile: 64 nodes x (64 feats x 2 gates), K=128 single pass. 256 threads,
// thread tile 4 nodes x 4 feats x 2 gates = 32 accumulators.

__global__ __launch_bounds__(256) void k_cell(const float* __restrict__ aggX,
                                              const float* __restrict__ aggH,
                                              const float* __restrict__ W,   // layer base: [6][64][64]
                                              const float* __restrict__ b,   // layer base: [6][64]
                                              float* __restrict__ h) {
  __shared__ __align__(16) float As[128][68];   // [k][node], padded to dodge write conflicts
  __shared__ __align__(16) float Bu[128][64];   // [k][f]
  __shared__ __align__(16) float Bc[128][64];
  const int tid = threadIdx.x;
  const int bn0 = blockIdx.x * 64;

  // stage A transposed: rows k<64 from aggX, k>=64 from aggH
#pragma unroll
  for (int i = 0; i < 8; ++i) {
    int q = tid + i * 256;       // [0,2048)
    int node = q >> 5;           // [0,64)
    int k = (q & 31) * 4;        // 0..124
    int gn = bn0 + node;
    float4 v = make_float4(0.f, 0.f, 0.f, 0.f);
    if (gn < NN) {
      const float* p = (k < 64) ? (aggX + gn * 64 + k) : (aggH + gn * 64 + (k - 64));
      v = *(const float4*)p;
    }
    As[k + 0][node] = v.x;
    As[k + 1][node] = v.y;
    As[k + 2][node] = v.z;
    As[k + 3][node] = v.w;
  }
  // stage B: Bu rows 0..63 = W[2] (u_x), 64..127 = W[3] (u_h); Bc = W[4]/W[5]
#pragma unroll
  for (int i = 0; i < 8; ++i) {
    int q = tid + i * 256;       // [0,2048)
    int k = q >> 4;              // [0,128)
    int f = (q & 15) * 4;
    int kk = (k < 64) ? k : (k - 64);
    int gu = (k < 64) ? 2 : 3;
    int gc = (k < 64) ? 4 : 5;
    float4 u4 = *(const float4*)(W + gu * 4096 + kk * 64 + f);
    float4 c4 = *(const float4*)(W + gc * 4096 + kk * 64 + f);
    *(float4*)&Bu[k][f] = u4;
    *(float4*)&Bc[k][f] = c4;
  }
  __syncthreads();

  const int tx = tid & 15, ty = tid >> 4;
  const int f0 = tx * 4, n0 = ty * 4;
  float accu[4][4] = {};
  float accc[4][4] = {};
#pragma unroll 8
  for (int k = 0; k < 128; ++k) {
    float4 a4 = *(const float4*)&As[k][n0];
    float4 u4 = *(const float4*)&Bu[k][f0];
    float4 c4 = *(const float4*)&Bc[k][f0];
    float av[4] = {a4.x, a4.y, a4.z, a4.w};
    float uv[4] = {u4.x, u4.y, u4.z, u4.w};
    float cv[4] = {c4.x, c4.y, c4.z, c4.w};
#pragma unroll
    for (int i2 = 0; i2 < 4; ++i2)
#pragma unroll
      for (int j = 0; j < 4; ++j) {
        accu[i2][j] = fmaf(av[i2], uv[j], accu[i2][j]);
        accc[i2][j] = fmaf(av[i2], cv[j], accc[i2][j]);
      }
  }

  float bu_[4], bc_[4];
#pragma unroll
  for (int j = 0; j < 4; ++j) {
    bu_[j] = b[2 * 64 + f0 + j] + b[3 * 64 + f0 + j];
    bc_[j] = b[4 * 64 + f0 + j] + b[5 * 64 + f0 + j];
  }
#pragma unroll
  for (int i2 = 0; i2 < 4; ++i2) {
    int gn = bn0 + n0 + i2;
    if (gn >= NN) continue;
    float4 hv = *(const float4*)(h + gn * 64 + f0);
    float hb[4] = {hv.x, hv.y, hv.z, hv.w};
    float o[4];
#pragma unroll
    for (int j = 0; j < 4; ++j) {
      float pu = accu[i2][j] + bu_[j];
      float u = 1.f / (1.f + expf(-pu));
      float c = tanhf(accc[i2][j] + bc_[j]);
      o[j] = u * hb[j] + (1.f - u) * c;
    }
    *(float4*)(h + gn * 64 + f0) = make_float4(o[0], o[1], o[2], o[3]);
  }
}

// ---------------- launch ----------------

extern "C" void kernel_launch(void* const* d_in, const int* in_sizes, int n_in,
                              void* d_out, int out_size, void* d_ws, size_t ws_size,
                              hipStream_t stream) {
  const float* x  = (const float*)d_in[0];   // [T][N][F]
  const float* h0 = (const float*)d_in[1];   // [L][N][F]
  const float* W  = (const float*)d_in[2];   // [L][6][64][64]
  const float* b  = (const float*)d_in[3];   // [L][6][64]
  const int* src  = (const int*)d_in[4];
  const int* dst  = (const int*)d_in[5];
  float* out = (float*)d_out;

  // workspace: CSR only (~4.5 MB)
  char* w = (char*)d_ws;
  auto alloc = [&](size_t bytes) {
    char* p = w;
    w += (bytes + 255) & ~(size_t)255;
    return p;
  };
  int*   deg    = (int*)alloc((size_t)NN * 4);
  int*   rowptr = (int*)alloc((size_t)(NN + 1) * 4);
  int*   fill   = (int*)alloc((size_t)NN * 4);
  int*   bsum   = (int*)alloc(256 * 4);
  int*   boff   = (int*)alloc(256 * 4);
  float* invd   = (float*)alloc((size_t)NN * 4);
  int*   col    = (int*)alloc((size_t)EE * 4);

  // agg scratch lives in d_out's x-region (overwritten by the final x copy)
  float* aggX  = out + (size_t)0 * NF;
  float* aggA  = out + (size_t)1 * NF;   // agg of layer-0 h (ping)
  float* aggB  = out + (size_t)2 * NF;   // pong
  float* aggH1 = out + (size_t)3 * NF;
  float* hbuf  = out + (size_t)TT * NF;  // [L][N][F] final hidden storage (in place)

  hipMemsetAsync(deg, 0, (size_t)NN * 4, stream);
  k_deg<<<(EE + 255) / 256, 256, 0, stream>>>(dst, deg);
  int nb = (NN + 255) / 256;  // 196
  k_scan1<<<nb, 256, 0, stream>>>(deg, rowptr, bsum);
  k_scan2<<<1, 256, 0, stream>>>(bsum, boff, nb);
  k_scan3<<<nb, 256, 0, stream>>>(deg, rowptr, fill, invd, boff);
  k_scatter<<<(EE + 255) / 256, 256, 0, stream>>>(src, dst, fill, col);

  hipMemcpyAsync(hbuf, h0, (size_t)LL * NF * 4, hipMemcpyDeviceToDevice, stream);

  const int gagg  = (NN + 3) / 4;    // 12500 blocks, wave per node
  const int gcell = (NN + 63) / 64;  // 782 blocks

  // initial aggregation of layer-0 hidden
  k_agg<<<gagg, 256, 0, stream>>>(hbuf, aggA, rowptr, col, invd);

  float* aggP = aggA;
  float* aggQ = aggB;
  for (int t = 0; t < TT; ++t) {
    // layer 0: xin = x[t]
    k_agg<<<gagg, 256, 0, stream>>>(x + (size_t)t * NF, aggX, rowptr, col, invd);
    k_cell<<<gcell, 256, 0, stream>>>(aggX, aggP, W + 0 * 6 * 4096, b + 0 * 6 * 64, hbuf);
    // agg(h0') — used as layer-1 xin-agg now AND as layer-0 h-agg next step
    k_agg<<<gagg, 256, 0, stream>>>(hbuf, aggQ, rowptr, col, invd);
    // layer 1
    k_agg<<<gagg, 256, 0, stream>>>(hbuf + NF, aggH1, rowptr, col, invd);
    k_cell<<<gcell, 256, 0, stream>>>(aggQ, aggH1, W + 1 * 6 * 4096, b + 1 * 6 * 64, hbuf + NF);
    float* tmp = aggP; aggP = aggQ; aggQ = tmp;
  }

  // output x passthrough (overwrites the agg scratch region with exact input bytes)
  hipMemcpyAsync(out, x, (size_t)TT * NF * 4, hipMemcpyDeviceToDevice, stream);
}

// Round 2
// 2303.679 us; speedup vs baseline: 1.2542x; 1.2542x over previous
//
#include <hip/hip_runtime.h>
#include <math.h>

#define NN 50000
#define EE 800000
#define FF 64
#define LL 2
#define TT 12
#define NF (NN * FF)

// ---------------- CSR build ----------------

__global__ __launch_bounds__(256) void k_deg(const int* __restrict__ dst, int* __restrict__ deg) {
  int e = blockIdx.x * 256 + threadIdx.x;
  if (e < EE) atomicAdd(&deg[dst[e]], 1);
}

__global__ __launch_bounds__(256) void k_scan1(const int* __restrict__ deg, int* __restrict__ rowptr,
                                               int* __restrict__ bsum) {
  __shared__ int s[256];
  int i = blockIdx.x * 256 + threadIdx.x;
  int v = (i < NN) ? deg[i] : 0;
  s[threadIdx.x] = v;
  __syncthreads();
  for (int off = 1; off < 256; off <<= 1) {
    int t = (threadIdx.x >= off) ? s[threadIdx.x - off] : 0;
    __syncthreads();
    s[threadIdx.x] += t;
    __syncthreads();
  }
  if (i < NN) rowptr[i + 1] = s[threadIdx.x];
  if (threadIdx.x == 255) bsum[blockIdx.x] = s[255];
}

__global__ __launch_bounds__(256) void k_scan2(const int* __restrict__ bsum, int* __restrict__ boff, int nb) {
  __shared__ int s[256];
  int v = (threadIdx.x < nb) ? bsum[threadIdx.x] : 0;
  s[threadIdx.x] = v;
  __syncthreads();
  for (int off = 1; off < 256; off <<= 1) {
    int t = (threadIdx.x >= off) ? s[threadIdx.x - off] : 0;
    __syncthreads();
    s[threadIdx.x] += t;
    __syncthreads();
  }
  boff[threadIdx.x] = s[threadIdx.x] - v;  // exclusive
}

__global__ __launch_bounds__(256) void k_scan3(const int* __restrict__ deg, int* __restrict__ rowptr,
                                               int* __restrict__ fill, float* __restrict__ invdeg,
                                               const int* __restrict__ boff) {
  int i = blockIdx.x * 256 + threadIdx.x;
  if (i >= NN) return;
  int incl = rowptr[i + 1] + boff[blockIdx.x];
  rowptr[i + 1] = incl;
  int d = deg[i];
  fill[i] = incl - d;
  invdeg[i] = (d > 0) ? (1.0f / (float)d) : 0.0f;
  if (i == 0) rowptr[0] = 0;
}

__global__ __launch_bounds__(256) void k_scatter(const int* __restrict__ src, const int* __restrict__ dst,
                                                 int* __restrict__ fill, int* __restrict__ col) {
  int e = blockIdx.x * 256 + threadIdx.x;
  if (e >= EE) return;
  int slot = atomicAdd(&fill[dst[e]], 1);
  col[slot] = src[e];
}

// ---------------- mean aggregation, float4-gather, wave per node ----------------
// Wave layout: g = lane>>4 selects one of 4 edge slots, l = lane&15 selects a
// 16-byte feature slice. Per iteration the wave gathers 4 full 256B rows via
// dwordx4 loads (fully coalesced per 16-lane group). Butterfly shfl_xor over
// the g-groups produces the full 64-float sum.

__device__ __forceinline__ void f4add(float4& a, const float4 b) {
  a.x += b.x; a.y += b.y; a.z += b.z; a.w += b.w;
}
__device__ __forceinline__ void f4red(float4& a) {
  a.x += __shfl_xor(a.x, 16); a.y += __shfl_xor(a.y, 16);
  a.z += __shfl_xor(a.z, 16); a.w += __shfl_xor(a.w, 16);
  a.x += __shfl_xor(a.x, 32); a.y += __shfl_xor(a.y, 32);
  a.z += __shfl_xor(a.z, 32); a.w += __shfl_xor(a.w, 32);
}

__global__ __launch_bounds__(256) void k_agg1(const float* __restrict__ feat, float* __restrict__ outp,
                                              const int* __restrict__ rowptr, const int* __restrict__ col,
                                              const float* __restrict__ invd) {
  int v = blockIdx.x * 4 + (threadIdx.x >> 6);
  if (v >= NN) return;
  int lane = threadIdx.x & 63;
  int g = lane >> 4, l = lane & 15;
  int s = rowptr[v], e = rowptr[v + 1];
  float4 acc = make_float4(0.f, 0.f, 0.f, 0.f);
  int i = s + g;
  for (; i + 4 < e; i += 8) {  // 2 edges per group in flight
    int c0 = col[i];
    int c1 = col[i + 4];
    float4 v0 = *(const float4*)(feat + (size_t)c0 * 64 + l * 4);
    float4 v1 = *(const float4*)(feat + (size_t)c1 * 64 + l * 4);
    f4add(acc, v0);
    f4add(acc, v1);
  }
  if (i < e) {
    int c0 = col[i];
    float4 v0 = *(const float4*)(feat + (size_t)c0 * 64 + l * 4);
    f4add(acc, v0);
  }
  f4red(acc);
  if (g == 0) {
    float sc = invd[v];
    *(float4*)(outp + (size_t)v * 64 + l * 4) =
        make_float4(acc.x * sc, acc.y * sc, acc.z * sc, acc.w * sc);
  }
}

// batched x-agg: blockIdx.y = t selects the time slice; writes into out[t] slot
__global__ __launch_bounds__(256) void k_aggx(const float* __restrict__ x, float* __restrict__ outbase,
                                              const int* __restrict__ rowptr, const int* __restrict__ col,
                                              const float* __restrict__ invd) {
  int v = blockIdx.x * 4 + (threadIdx.x >> 6);
  if (v >= NN) return;
  const float* feat = x + (size_t)blockIdx.y * NF;
  float* outp = outbase + (size_t)blockIdx.y * NF;
  int lane = threadIdx.x & 63;
  int g = lane >> 4, l = lane & 15;
  int s = rowptr[v], e = rowptr[v + 1];
  float4 acc = make_float4(0.f, 0.f, 0.f, 0.f);
  int i = s + g;
  for (; i + 4 < e; i += 8) {
    int c0 = col[i];
    int c1 = col[i + 4];
    float4 v0 = *(const float4*)(feat + (size_t)c0 * 64 + l * 4);
    float4 v1 = *(const float4*)(feat + (size_t)c1 * 64 + l * 4);
    f4add(acc, v0);
    f4add(acc, v1);
  }
  if (i < e) {
    int c0 = col[i];
    float4 v0 = *(const float4*)(feat + (size_t)c0 * 64 + l * 4);
    f4add(acc, v0);
  }
  f4red(acc);
  if (g == 0) {
    float sc = invd[v];
    *(float4*)(outp + (size_t)v * 64 + l * 4) =
        make_float4(acc.x * sc, acc.y * sc, acc.z * sc, acc.w * sc);
  }
}

// dual-feature agg: aggregates h0 and h1 with one col pass (shared graph)
__global__ __launch_bounds__(256) void k_agg2(const float* __restrict__ f0, const float* __restrict__ f1,
                                              float* __restrict__ o0, float* __restrict__ o1,
                                              const int* __restrict__ rowptr, const int* __restrict__ col,
                                              const float* __restrict__ invd) {
  int v = blockIdx.x * 4 + (threadIdx.x >> 6);
  if (v >= NN) return;
  int lane = threadIdx.x & 63;
  int g = lane >> 4, l = lane & 15;
  int s = rowptr[v], e = rowptr[v + 1];
  float4 a0 = make_float4(0.f, 0.f, 0.f, 0.f);
  float4 a1 = make_float4(0.f, 0.f, 0.f, 0.f);
  int i = s + g;
  for (; i + 4 < e; i += 8) {
    int c0 = col[i];
    int c1 = col[i + 4];
    size_t r0 = (size_t)c0 * 64 + l * 4;
    size_t r1 = (size_t)c1 * 64 + l * 4;
    float4 u0 = *(const float4*)(f0 + r0);
    float4 w0 = *(const float4*)(f1 + r0);
    float4 u1 = *(const float4*)(f0 + r1);
    float4 w1 = *(const float4*)(f1 + r1);
    f4add(a0, u0); f4add(a1, w0);
    f4add(a0, u1); f4add(a1, w1);
  }
  if (i < e) {
    int c0 = col[i];
    size_t r0 = (size_t)c0 * 64 + l * 4;
    float4 u0 = *(const float4*)(f0 + r0);
    float4 w0 = *(const float4*)(f1 + r0);
    f4add(a0, u0); f4add(a1, w0);
  }
  f4red(a0);
  f4red(a1);
  float sc = invd[v];
  if (g == 0)
    *(float4*)(o0 + (size_t)v * 64 + l * 4) =
        make_float4(a0.x * sc, a0.y * sc, a0.z * sc, a0.w * sc);
  if (g == 1)
    *(float4*)(o1 + (size_t)v * 64 + l * 4) =
        make_float4(a1.x * sc, a1.y * sc, a1.z * sc, a1.w * sc);
}

// ---------------- fused GEMM + GRU cell ----------------
// pre_u = aggX@W[2] + aggH@W[3] + b2+b3 ; pre_c = aggX@W[4] + aggH@W[5] + b4+b5
// h' = sigmoid(pre_u)*h + (1-sigmoid(pre_u))*tanh(pre_c), in place over h.
// K split into 2 phases of 64 so LDS = 34.8+16+16 = 66.8 KB -> 2 blocks/CU.

__global__ __launch_bounds__(256) void k_cell(const float* __restrict__ aggX,
                                              const float* __restrict__ aggH,
                                              const float* __restrict__ W,   // layer base: [6][64][64]
                                              const float* __restrict__ b,   // layer base: [6][64]
                                              float* __restrict__ h) {
  __shared__ __align__(16) float As[128][68];   // [k][node]
  __shared__ __align__(16) float Bu[64][64];    // phase k-rows for u
  __shared__ __align__(16) float Bc[64][64];    // phase k-rows for c
  const int tid = threadIdx.x;
  const int bn0 = blockIdx.x * 64;

  // stage A transposed: rows k<64 from aggX, k>=64 from aggH
#pragma unroll
  for (int i = 0; i < 8; ++i) {
    int q = tid + i * 256;       // [0,2048)
    int node = q >> 5;           // [0,64)
    int k = (q & 31) * 4;        // 0..124
    int gn = bn0 + node;
    float4 v = make_float4(0.f, 0.f, 0.f, 0.f);
    if (gn < NN) {
      const float* p = (k < 64) ? (aggX + (size_t)gn * 64 + k) : (aggH + (size_t)gn * 64 + (k - 64));
      v = *(const float4*)p;
    }
    As[k + 0][node] = v.x;
    As[k + 1][node] = v.y;
    As[k + 2][node] = v.z;
    As[k + 3][node] = v.w;
  }

  const int tx = tid & 15, ty = tid >> 4;
  const int f0 = tx * 4, n0 = ty * 4;
  float accu[4][4] = {};
  float accc[4][4] = {};

#pragma unroll
  for (int p = 0; p < 2; ++p) {
    // stage B for k-rows [p*64, p*64+64): u gate = W[2+p], c gate = W[4+p]
#pragma unroll
    for (int i = 0; i < 4; ++i) {
      int q = tid + i * 256;     // [0,1024)
      int k = q >> 4;            // [0,64)
      int f = (q & 15) * 4;
      *(float4*)&Bu[k][f] = *(const float4*)(W + (size_t)(2 + p) * 4096 + k * 64 + f);
      *(float4*)&Bc[k][f] = *(const float4*)(W + (size_t)(4 + p) * 4096 + k * 64 + f);
    }
    __syncthreads();
#pragma unroll 8
    for (int k = 0; k < 64; ++k) {
      float4 a4 = *(const float4*)&As[p * 64 + k][n0];
      float4 u4 = *(const float4*)&Bu[k][f0];
      float4 c4 = *(const float4*)&Bc[k][f0];
      float av[4] = {a4.x, a4.y, a4.z, a4.w};
      float uv[4] = {u4.x, u4.y, u4.z, u4.w};
      float cv[4] = {c4.x, c4.y, c4.z, c4.w};
#pragma unroll
      for (int i2 = 0; i2 < 4; ++i2)
#pragma unroll
        for (int j = 0; j < 4; ++j) {
          accu[i2][j] = fmaf(av[i2], uv[j], accu[i2][j]);
          accc[i2][j] = fmaf(av[i2], cv[j], accc[i2][j]);
        }
    }
    __syncthreads();
  }

  float bu_[4], bc_[4];
#pragma unroll
  for (int j = 0; j < 4; ++j) {
    bu_[j] = b[2 * 64 + f0 + j] + b[3 * 64 + f0 + j];
    bc_[j] = b[4 * 64 + f0 + j] + b[5 * 64 + f0 + j];
  }
#pragma unroll
  for (int i2 = 0; i2 < 4; ++i2) {
    int gn = bn0 + n0 + i2;
    if (gn >= NN) continue;
    float4 hv = *(const float4*)(h + (size_t)gn * 64 + f0);
    float hb[4] = {hv.x, hv.y, hv.z, hv.w};
    float o[4];
#pragma unroll
    for (int j = 0; j < 4; ++j) {
      float pu = accu[i2][j] + bu_[j];
      float u = 1.f / (1.f + expf(-pu));
      float c = tanhf(accc[i2][j] + bc_[j]);
      o[j] = u * hb[j] + (1.f - u) * c;
    }
    *(float4*)(h + (size_t)gn * 64 + f0) = make_float4(o[0], o[1], o[2], o[3]);
  }
}

// ---------------- launch ----------------

extern "C" void kernel_launch(void* const* d_in, const int* in_sizes, int n_in,
                              void* d_out, int out_size, void* d_ws, size_t ws_size,
                              hipStream_t stream) {
  const float* x  = (const float*)d_in[0];   // [T][N][F]
  const float* h0 = (const float*)d_in[1];   // [L][N][F]
  const float* W  = (const float*)d_in[2];   // [L][6][64][64]
  const float* b  = (const float*)d_in[3];   // [L][6][64]
  const int* src  = (const int*)d_in[4];
  const int* dst  = (const int*)d_in[5];
  float* out = (float*)d_out;

  char* w = (char*)d_ws;
  auto alloc = [&](size_t bytes) {
    char* p = w;
    w += (bytes + 255) & ~(size_t)255;
    return p;
  };
  int*   deg    = (int*)alloc((size_t)NN * 4);
  int*   rowptr = (int*)alloc((size_t)(NN + 1) * 4);
  int*   fill   = (int*)alloc((size_t)NN * 4);
  int*   bsum   = (int*)alloc(256 * 4);
  int*   boff   = (int*)alloc(256 * 4);
  float* invd   = (float*)alloc((size_t)NN * 4);
  int*   col    = (int*)alloc((size_t)EE * 4);
  float* aggP   = (float*)alloc((size_t)NF * 4);   // agg of layer-0 h (ping)
  float* aggQ   = (float*)alloc((size_t)NF * 4);   // pong
  float* aggH1  = (float*)alloc((size_t)NF * 4);   // agg of layer-1 h

  // 12 x-agg buffers live in d_out's x region (slot t), overwritten by the
  // final x passthrough copy after their last use at step t.
  float* xagg = out;
  float* hbuf = out + (size_t)TT * NF;  // [L][N][F] final hidden storage, updated in place

  hipMemsetAsync(deg, 0, (size_t)NN * 4, stream);
  k_deg<<<(EE + 255) / 256, 256, 0, stream>>>(dst, deg);
  int nb = (NN + 255) / 256;  // 196
  k_scan1<<<nb, 256, 0, stream>>>(deg, rowptr, bsum);
  k_scan2<<<1, 256, 0, stream>>>(bsum, boff, nb);
  k_scan3<<<nb, 256, 0, stream>>>(deg, rowptr, fill, invd, boff);
  k_scatter<<<(EE + 255) / 256, 256, 0, stream>>>(src, dst, fill, col);

  hipMemcpyAsync(hbuf, h0, (size_t)LL * NF * 4, hipMemcpyDeviceToDevice, stream);

  const int gagg  = (NN + 3) / 4;    // 12500 blocks, wave per node
  const int gcell = (NN + 63) / 64;  // 782 blocks

  // all 12 x-aggs at once (independent of the recurrence)
  dim3 gx(gagg, TT, 1);
  k_aggx<<<gx, 256, 0, stream>>>(x, xagg, rowptr, col, invd);

  // initial aggregation of layer-0 hidden
  k_agg1<<<gagg, 256, 0, stream>>>(hbuf, aggP, rowptr, col, invd);

  for (int t = 0; t < TT; ++t) {
    // layer 0
    k_cell<<<gcell, 256, 0, stream>>>(xagg + (size_t)t * NF, aggP, W + 0 * 6 * 4096, b + 0 * 6 * 64, hbuf);
    // agg(h0') (-> layer-1 input agg now, layer-0 h agg next step) + agg(h1)
    k_agg2<<<gagg, 256, 0, stream>>>(hbuf, hbuf + NF, aggQ, aggH1, rowptr, col, invd);
    // layer 1
    k_cell<<<gcell, 256, 0, stream>>>(aggQ, aggH1, W + 1 * 6 * 4096, b + 1 * 6 * 64, hbuf + NF);
    float* tmp = aggP; aggP = aggQ; aggQ = tmp;
  }

  // output x passthrough (overwrites the x-agg scratch with exact input bytes)
  hipMemcpyAsync(out, x, (size_t)TT * NF * 4, hipMemcpyDeviceToDevice, stream);
}

// Round 4
// 2267.651 us; speedup vs baseline: 1.2742x; 1.0159x over previous
//
#include <hip/hip_runtime.h>
#include <math.h>

#define NN 50000
#define EE 800000
#define FF 64
#define LL 2
#define TT 12
#define NF (NN * FF)

// ---------------- CSR build ----------------

__global__ __launch_bounds__(256) void k_deg(const int* __restrict__ dst, int* __restrict__ deg) {
  int e = blockIdx.x * 256 + threadIdx.x;
  if (e < EE) atomicAdd(&deg[dst[e]], 1);
}

__global__ __launch_bounds__(256) void k_scan1(const int* __restrict__ deg, int* __restrict__ rowptr,
                                               int* __restrict__ bsum) {
  __shared__ int s[256];
  int i = blockIdx.x * 256 + threadIdx.x;
  int v = (i < NN) ? deg[i] : 0;
  s[threadIdx.x] = v;
  __syncthreads();
  for (int off = 1; off < 256; off <<= 1) {
    int t = (threadIdx.x >= off) ? s[threadIdx.x - off] : 0;
    __syncthreads();
    s[threadIdx.x] += t;
    __syncthreads();
  }
  if (i < NN) rowptr[i + 1] = s[threadIdx.x];
  if (threadIdx.x == 255) bsum[blockIdx.x] = s[255];
}

__global__ __launch_bounds__(256) void k_scan2(const int* __restrict__ bsum, int* __restrict__ boff, int nb) {
  __shared__ int s[256];
  int v = (threadIdx.x < nb) ? bsum[threadIdx.x] : 0;
  s[threadIdx.x] = v;
  __syncthreads();
  for (int off = 1; off < 256; off <<= 1) {
    int t = (threadIdx.x >= off) ? s[threadIdx.x - off] : 0;
    __syncthreads();
    s[threadIdx.x] += t;
    __syncthreads();
  }
  boff[threadIdx.x] = s[threadIdx.x] - v;  // exclusive
}

__global__ __launch_bounds__(256) void k_scan3(const int* __restrict__ deg, int* __restrict__ rowptr,
                                               int* __restrict__ fill, float* __restrict__ invdeg,
                                               const int* __restrict__ boff) {
  int i = blockIdx.x * 256 + threadIdx.x;
  if (i >= NN) return;
  int incl = rowptr[i + 1] + boff[blockIdx.x];
  rowptr[i + 1] = incl;
  int d = deg[i];
  fill[i] = incl - d;
  invdeg[i] = (d > 0) ? (1.0f / (float)d) : 0.0f;
  if (i == 0) rowptr[0] = 0;
}

__global__ __launch_bounds__(256) void k_scatter(const int* __restrict__ src, const int* __restrict__ dst,
                                                 int* __restrict__ fill, int* __restrict__ col) {
  int e = blockIdx.x * 256 + threadIdx.x;
  if (e >= EE) return;
  int slot = atomicAdd(&fill[dst[e]], 1);
  col[slot] = src[e];
}

// ---------------- mean aggregation, 4-deep pipelined float4 gather ----------------
// Wave per node. lane = g*16 + l: group g (of 4) takes a CONTIGUOUS quarter of
// the node's edge list; l selects a 16B feature slice. Each group prefetches 4
// col indices then issues 4 independent 256B row gathers -> up to 16 rows in
// flight per wave. Butterfly shfl_xor over groups at the end.

__device__ __forceinline__ void f4add(float4& a, const float4 b) {
  a.x += b.x; a.y += b.y; a.z += b.z; a.w += b.w;
}
__device__ __forceinline__ void f4red(float4& a) {
  a.x += __shfl_xor(a.x, 16); a.y += __shfl_xor(a.y, 16);
  a.z += __shfl_xor(a.z, 16); a.w += __shfl_xor(a.w, 16);
  a.x += __shfl_xor(a.x, 32); a.y += __shfl_xor(a.y, 32);
  a.z += __shfl_xor(a.z, 32); a.w += __shfl_xor(a.w, 32);
}

__device__ __forceinline__ float4 gather_seg(const float* __restrict__ feat,
                                             const int* __restrict__ col,
                                             int b, int n, int l) {
  float4 acc = make_float4(0.f, 0.f, 0.f, 0.f);
  int i = b, e = b + n;
  for (; i + 4 <= e; i += 4) {
    int c0 = col[i], c1 = col[i + 1], c2 = col[i + 2], c3 = col[i + 3];
    float4 v0 = *(const float4*)(feat + (size_t)c0 * 64 + l * 4);
    float4 v1 = *(const float4*)(feat + (size_t)c1 * 64 + l * 4);
    float4 v2 = *(const float4*)(feat + (size_t)c2 * 64 + l * 4);
    float4 v3 = *(const float4*)(feat + (size_t)c3 * 64 + l * 4);
    f4add(acc, v0); f4add(acc, v1); f4add(acc, v2); f4add(acc, v3);
  }
  if (i + 2 <= e) {
    int c0 = col[i], c1 = col[i + 1];
    float4 v0 = *(const float4*)(feat + (size_t)c0 * 64 + l * 4);
    float4 v1 = *(const float4*)(feat + (size_t)c1 * 64 + l * 4);
    f4add(acc, v0); f4add(acc, v1);
    i += 2;
  }
  if (i < e) {
    int c0 = col[i];
    float4 v0 = *(const float4*)(feat + (size_t)c0 * 64 + l * 4);
    f4add(acc, v0);
  }
  return acc;
}

__device__ __forceinline__ void agg_node(const float* __restrict__ feat, float* __restrict__ outp,
                                         const int* __restrict__ rowptr, const int* __restrict__ col,
                                         const float* __restrict__ invd, int v, int lane) {
  int g = lane >> 4, l = lane & 15;
  int s = rowptr[v], e = rowptr[v + 1];
  int len = e - s;
  int q = len >> 2, r = len & 3;
  int b = s + g * q + min(g, r);
  int n = q + (g < r ? 1 : 0);
  float4 acc = gather_seg(feat, col, b, n, l);
  f4red(acc);
  if (g == 0) {
    float sc = invd[v];
    *(float4*)(outp + (size_t)v * 64 + l * 4) =
        make_float4(acc.x * sc, acc.y * sc, acc.z * sc, acc.w * sc);
  }
}

// batched x-agg: blockIdx.y = t
__global__ __launch_bounds__(256) void k_aggx(const float* __restrict__ x, float* __restrict__ outbase,
                                              const int* __restrict__ rowptr, const int* __restrict__ col,
                                              const float* __restrict__ invd) {
  int v = blockIdx.x * 4 + (threadIdx.x >> 6);
  if (v >= NN) return;
  agg_node(x + (size_t)blockIdx.y * NF, outbase + (size_t)blockIdx.y * NF,
           rowptr, col, invd, v, threadIdx.x & 63);
}

// 1-or-2-slice h-agg: blockIdx.y picks (f0->o0) or (f1->o1)
__global__ __launch_bounds__(256) void k_aggh(const float* __restrict__ f0, const float* __restrict__ f1,
                                              float* __restrict__ o0, float* __restrict__ o1,
                                              const int* __restrict__ rowptr, const int* __restrict__ col,
                                              const float* __restrict__ invd) {
  int v = blockIdx.x * 4 + (threadIdx.x >> 6);
  if (v >= NN) return;
  const float* feat = blockIdx.y ? f1 : f0;
  float* outp = blockIdx.y ? o1 : o0;
  agg_node(feat, outp, rowptr, col, invd, v, threadIdx.x & 63);
}

// ---------------- fused GEMM + GRU cell ----------------

__global__ __launch_bounds__(256) void k_cell(const float* __restrict__ aggX,
                                              const float* __restrict__ aggH,
                                              const float* __restrict__ W,   // layer base: [6][64][64]
                                              const float* __restrict__ b,   // layer base: [6][64]
                                              float* __restrict__ h) {
  __shared__ __align__(16) float As[128][68];   // [k][node]
  __shared__ __align__(16) float Bu[64][64];
  __shared__ __align__(16) float Bc[64][64];
  const int tid = threadIdx.x;
  const int bn0 = blockIdx.x * 64;

#pragma unroll
  for (int i = 0; i < 8; ++i) {
    int q = tid + i * 256;
    int node = q >> 5;
    int k = (q & 31) * 4;
    int gn = bn0 + node;
    float4 v = make_float4(0.f, 0.f, 0.f, 0.f);
    if (gn < NN) {
      const float* p = (k < 64) ? (aggX + (size_t)gn * 64 + k) : (aggH + (size_t)gn * 64 + (k - 64));
      v = *(const float4*)p;
    }
    As[k + 0][node] = v.x;
    As[k + 1][node] = v.y;
    As[k + 2][node] = v.z;
    As[k + 3][node] = v.w;
  }

  const int tx = tid & 15, ty = tid >> 4;
  const int f0 = tx * 4, n0 = ty * 4;
  float accu[4][4] = {};
  float accc[4][4] = {};

#pragma unroll
  for (int p = 0; p < 2; ++p) {
#pragma unroll
    for (int i = 0; i < 4; ++i) {
      int q = tid + i * 256;
      int k = q >> 4;
      int f = (q & 15) * 4;
      *(float4*)&Bu[k][f] = *(const float4*)(W + (size_t)(2 + p) * 4096 + k * 64 + f);
      *(float4*)&Bc[k][f] = *(const float4*)(W + (size_t)(4 + p) * 4096 + k * 64 + f);
    }
    __syncthreads();
#pragma unroll 8
    for (int k = 0; k < 64; ++k) {
      float4 a4 = *(const float4*)&As[p * 64 + k][n0];
      float4 u4 = *(const float4*)&Bu[k][f0];
      float4 c4 = *(const float4*)&Bc[k][f0];
      float av[4] = {a4.x, a4.y, a4.z, a4.w};
      float uv[4] = {u4.x, u4.y, u4.z, u4.w};
      float cv[4] = {c4.x, c4.y, c4.z, c4.w};
#pragma unroll
      for (int i2 = 0; i2 < 4; ++i2)
#pragma unroll
        for (int j = 0; j < 4; ++j) {
          accu[i2][j] = fmaf(av[i2], uv[j], accu[i2][j]);
          accc[i2][j] = fmaf(av[i2], cv[j], accc[i2][j]);
        }
    }
    __syncthreads();
  }

  float bu_[4], bc_[4];
#pragma unroll
  for (int j = 0; j < 4; ++j) {
    bu_[j] = b[2 * 64 + f0 + j] + b[3 * 64 + f0 + j];
    bc_[j] = b[4 * 64 + f0 + j] + b[5 * 64 + f0 + j];
  }
#pragma unroll
  for (int i2 = 0; i2 < 4; ++i2) {
    int gn = bn0 + n0 + i2;
    if (gn >= NN) continue;
    float4 hv = *(const float4*)(h + (size_t)gn * 64 + f0);
    float hb[4] = {hv.x, hv.y, hv.z, hv.w};
    float o[4];
#pragma unroll
    for (int j = 0; j < 4; ++j) {
      float pu = accu[i2][j] + bu_[j];
      float u = 1.f / (1.f + expf(-pu));
      float c = tanhf(accc[i2][j] + bc_[j]);
      o[j] = u * hb[j] + (1.f - u) * c;
    }
    *(float4*)(h + (size_t)gn * 64 + f0) = make_float4(o[0], o[1], o[2], o[3]);
  }
}

// ---------------- launch ----------------

extern "C" void kernel_launch(void* const* d_in, const int* in_sizes, int n_in,
                              void* d_out, int out_size, void* d_ws, size_t ws_size,
                              hipStream_t stream) {
  const float* x  = (const float*)d_in[0];   // [T][N][F]
  const float* h0 = (const float*)d_in[1];   // [L][N][F]
  const float* W  = (const float*)d_in[2];   // [L][6][64][64]
  const float* b  = (const float*)d_in[3];   // [L][6][64]
  const int* src  = (const int*)d_in[4];
  const int* dst  = (const int*)d_in[5];
  float* out = (float*)d_out;

  char* w = (char*)d_ws;
  auto alloc = [&](size_t bytes) {
    char* p = w;
    w += (bytes + 255) & ~(size_t)255;
    return p;
  };
  int*   deg    = (int*)alloc((size_t)NN * 4);
  int*   rowptr = (int*)alloc((size_t)(NN + 1) * 4);
  int*   fill   = (int*)alloc((size_t)NN * 4);
  int*   bsum   = (int*)alloc(256 * 4);
  int*   boff   = (int*)alloc(256 * 4);
  float* invd   = (float*)alloc((size_t)NN * 4);
  int*   col    = (int*)alloc((size_t)EE * 4);
  float* aggP   = (float*)alloc((size_t)NF * 4);
  float* aggQ   = (float*)alloc((size_t)NF * 4);
  float* aggH1  = (float*)alloc((size_t)NF * 4);

  float* xagg = out;                     // d_out x region, overwritten at the end
  float* hbuf = out + (size_t)TT * NF;   // [L][N][F] hidden, updated in place

  hipMemsetAsync(deg, 0, (size_t)NN * 4, stream);
  k_deg<<<(EE + 255) / 256, 256, 0, stream>>>(dst, deg);
  int nb = (NN + 255) / 256;  // 196
  k_scan1<<<nb, 256, 0, stream>>>(deg, rowptr, bsum);
  k_scan2<<<1, 256, 0, stream>>>(bsum, boff, nb);
  k_scan3<<<nb, 256, 0, stream>>>(deg, rowptr, fill, invd, boff);
  k_scatter<<<(EE + 255) / 256, 256, 0, stream>>>(src, dst, fill, col);

  hipMemcpyAsync(hbuf, h0, (size_t)LL * NF * 4, hipMemcpyDeviceToDevice, stream);

  const int gagg  = (NN + 3) / 4;    // 12500
  const int gcell = (NN + 63) / 64;  // 782

  dim3 gx(gagg, TT, 1);
  k_aggx<<<gx, 256, 0, stream>>>(x, xagg, rowptr, col, invd);

  // initial agg of layer-0 hidden
  k_aggh<<<dim3(gagg, 1, 1), 256, 0, stream>>>(hbuf, hbuf, aggP, aggP, rowptr, col, invd);

  for (int t = 0; t < TT; ++t) {
    k_cell<<<gcell, 256, 0, stream>>>(xagg + (size_t)t * NF, aggP, W + 0 * 6 * 4096, b + 0 * 6 * 64, hbuf);
    // y=0: agg(h0') -> aggQ ; y=1: agg(h1) -> aggH1
    k_aggh<<<dim3(gagg, 2, 1), 256, 0, stream>>>(hbuf, hbuf + NF, aggQ, aggH1, rowptr, col, invd);
    k_cell<<<gcell, 256, 0, stream>>>(aggQ, aggH1, W + 1 * 6 * 4096, b + 1 * 6 * 64, hbuf + NF);
    float* tmp = aggP; aggP = aggQ; aggQ = tmp;
  }

  hipMemcpyAsync(out, x, (size_t)TT * NF * 4, hipMemcpyDeviceToDevice, stream);
}